// Round 15
// baseline (456.177 us; speedup 1.0000x reference)
//
#include <hip/hip_runtime.h>
#include <cstdint>
#include <cstddef>

#define D_MODEL 1024
#define NH      16
#define HD      64
#define B_SZ    32
#define SEQ     1500
#define MROWS   (B_SZ * SEQ)   // 48000
#define KD      1024
#define NCH     16             // s-chunks per batch (R10-proven)
#define PSTR    68             // part stride: pv[64], m, l, pad2

typedef __attribute__((ext_vector_type(8))) short bf16x8;
typedef __attribute__((ext_vector_type(4))) float f32x4;
typedef unsigned short u16;

__device__ __forceinline__ u16 f2b(float f) {
  unsigned int x = __float_as_uint(f);
  x = (x + 0x7FFFu + ((x >> 16) & 1u)) >> 16;   // RNE
  return (u16)x;
}

__device__ __forceinline__ float b2f(u16 u) {
  return __uint_as_float((unsigned)u << 16);
}

// ---------------- cast + q-proj, role-split by block range (R10-proven) ----------------
#define ENC_BLOCKS 3000
#define W_BLOCKS   64
#define QPROJ_BLOCKS 64

__global__ __launch_bounds__(256) void cast_all_q(const float* __restrict__ enc,
                                                  const float* __restrict__ Wk,
                                                  const float* __restrict__ Wv,
                                                  const float* __restrict__ hs,
                                                  const float* __restrict__ Wq,
                                                  const float* __restrict__ bq,
                                                  u16* __restrict__ encb,
                                                  u16* __restrict__ wkvb,
                                                  float* __restrict__ qs) {
  const int tid = threadIdx.x;
  const int bid = blockIdx.x;
  if (bid < ENC_BLOCKS) {
    const float4* s4 = (const float4*)enc;
    const size_t base = (size_t)bid * 256 + tid;
    #pragma unroll
    for (int k = 0; k < 16; ++k) {
      size_t i = base + (size_t)k * (ENC_BLOCKS * 256);
      float4 a = s4[i];
      u16 u[4] = { f2b(a.x), f2b(a.y), f2b(a.z), f2b(a.w) };
      *reinterpret_cast<uint2*>(encb + i * 4) = *reinterpret_cast<const uint2*>(u);
    }
  } else if (bid < ENC_BLOCKS + W_BLOCKS) {
    const int wb = bid - ENC_BLOCKS;
    const size_t base = (size_t)wb * 256 + tid;
    const int NW4 = KD * KD / 4;           // 262,144 float4 per weight
    #pragma unroll
    for (int k = 0; k < 32; ++k) {
      size_t i = base + (size_t)k * (W_BLOCKS * 256);
      const float4* s4 = (i < (size_t)NW4) ? (const float4*)Wk : (const float4*)Wv;
      size_t j = (i < (size_t)NW4) ? i : i - NW4;
      float4 a = s4[j];
      u16 u[4] = { f2b(a.x), f2b(a.y), f2b(a.z), f2b(a.w) };
      *reinterpret_cast<uint2*>(wkvb + i * 4) = *reinterpret_cast<const uint2*>(u);
    }
  } else {
    const int qb = bid - ENC_BLOCKS - W_BLOCKS;
    const int n  = qb * 16 + (tid & 15);
    const int bb = tid >> 4;
    const float4* wp  = (const float4*)(Wq + (size_t)n * D_MODEL);
    const float4* x0p = (const float4*)(hs + (size_t)bb * D_MODEL);
    const float4* x1p = (const float4*)(hs + (size_t)(bb + 16) * D_MODEL);
    float a0 = 0.f, a1 = 0.f;
    #pragma unroll 8
    for (int i = 0; i < D_MODEL / 4; ++i) {
      float4 w = wp[i], x0 = x0p[i], x1 = x1p[i];
      a0 += w.x * x0.x + w.y * x0.y + w.z * x0.z + w.w * x0.w;
      a1 += w.x * x1.x + w.y * x1.y + w.z * x1.z + w.w * x1.w;
    }
    const float bqn = bq[n];
    qs[(size_t)bb * D_MODEL + n]        = (a0 + bqn) * 0.125f;   // SCALE^2 folded
    qs[(size_t)(bb + 16) * D_MODEL + n] = (a1 + bqn) * 0.125f;
  }
}

// ================= 128x256 bf16 MFMA GEMM, triple-buffered (R10-proven) =================
// New: optional bf16 side-copies of K,V (wbf != 0) for the attention pass.
#define GBM 128
#define GBN 256
#define GBK 32
#define GNT (KD / GBK)   // 32 K-tiles
#define AT  (GBM * GBK)  // 4096 u16 = 8 KB
#define BT  (GBN * GBK)  // 8192 u16 = 16 KB

__device__ __forceinline__ void stageA(const u16* __restrict__ Ag, u16* lbuf,
                                       long m0, int kt, int tid) {
  int c = tid;
  int r = c >> 2, cp = c & 3;
  int scp = cp ^ ((r >> 1) & 3);
  const u16* src = Ag + (m0 + r) * (long)KD + kt * GBK + scp * 8;
  __builtin_amdgcn_global_load_lds((const __attribute__((address_space(1))) void*)src,
      (__attribute__((address_space(3))) void*)(lbuf + (size_t)c * 8), 16, 0, 0);
}

__device__ __forceinline__ void stageB(const u16* __restrict__ Bg, u16* lbuf,
                                       int n0, int kt, int tid) {
  #pragma unroll
  for (int L = 0; L < 2; ++L) {
    int c = tid + L * 512;
    int r = c >> 2, cp = c & 3;
    int scp = cp ^ ((r >> 1) & 3);
    const u16* src = Bg + (size_t)(n0 + r) * KD + kt * GBK + scp * 8;
    __builtin_amdgcn_global_load_lds((const __attribute__((address_space(1))) void*)src,
        (__attribute__((address_space(3))) void*)(lbuf + (size_t)c * 8), 16, 0, 0);
  }
}

__device__ __forceinline__ bf16x8 ldFrag(const u16* buf, int row, int lane) {
  int r  = row + (lane & 15);
  int ch = (lane >> 4) ^ ((r >> 1) & 3);
  return *(const bf16x8*)(buf + (size_t)r * GBK + ch * 8);
}

__global__ __launch_bounds__(512, 4) void gemm_kv(const u16* __restrict__ A,
                                                  const u16* __restrict__ Bm,
                                                  const float* __restrict__ bv,
                                                  float* __restrict__ Kout,
                                                  float* __restrict__ Vout,
                                                  u16* __restrict__ Kb,
                                                  u16* __restrict__ Vb,
                                                  int wbf) {
  __shared__ __align__(16) char smem[3 * (GBM + GBN) * GBK * 2];   // 72 KiB
  u16* sAb = (u16*)smem;
  u16* sBb = sAb + 3 * AT;

  const int tid  = threadIdx.x;
  const int lane = tid & 63;
  const int wid  = tid >> 6;
  const int wr   = wid >> 2;
  const int wc   = wid & 3;

  int bx = (blockIdx.x & 7) * (gridDim.x >> 3) + (blockIdx.x >> 3);
  const int  mt = bx >> 3;
  const int  nt = bx & 7;
  const long m0 = (long)mt * GBM;
  const int  n0 = nt * GBN;

  stageA(A, sAb + 0 * AT, m0, 0, tid);
  stageB(Bm, sBb + 0 * BT, n0, 0, tid);
  stageA(A, sAb + 1 * AT, m0, 1, tid);
  stageB(Bm, sBb + 1 * BT, n0, 1, tid);
  stageA(A, sAb + 2 * AT, m0, 2, tid);
  stageB(Bm, sBb + 2 * BT, n0, 2, tid);

  f32x4 acc[4][4] = {};

  for (int t = 0; t < GNT; ++t) {
    if (t < GNT - 2)       { asm volatile("s_waitcnt vmcnt(6)" ::: "memory"); }
    else if (t == GNT - 2) { asm volatile("s_waitcnt vmcnt(3)" ::: "memory"); }
    else                   { asm volatile("s_waitcnt vmcnt(0)" ::: "memory"); }
    __builtin_amdgcn_s_barrier();

    const int  bi = t % 3;
    const u16* cA = sAb + bi * AT;
    const u16* cB = sBb + bi * BT;
    bf16x8 af[4], bfr[4];
    #pragma unroll
    for (int mf = 0; mf < 4; ++mf) af[mf]  = ldFrag(cA, wr * 64 + mf * 16, lane);
    #pragma unroll
    for (int nf = 0; nf < 4; ++nf) bfr[nf] = ldFrag(cB, wc * 64 + nf * 16, lane);
    asm volatile("s_waitcnt lgkmcnt(0)" ::: "memory");
    __builtin_amdgcn_s_barrier();

    if (t + 3 < GNT) {
      stageA(A, sAb + bi * AT, m0, t + 3, tid);
      stageB(Bm, sBb + bi * BT, n0, t + 3, tid);
    }

    #pragma unroll
    for (int mf = 0; mf < 4; ++mf)
      #pragma unroll
      for (int nf = 0; nf < 4; ++nf)
        acc[mf][nf] = __builtin_amdgcn_mfma_f32_16x16x32_bf16(af[mf], bfr[nf], acc[mf][nf], 0, 0, 0);
  }

  __syncthreads();
  float (*ep)[260] = (float(*)[260])smem;

  const bool isV = (nt >= 4);
  float* Co = isV ? Vout : Kout;
  u16*   Cb = isV ? Vb   : Kb;
  const int ncol0 = isV ? (n0 - 1024) : n0;
  float4 bias4[4];
  #pragma unroll
  for (int k = 0; k < 4; ++k) {
    int c4 = (tid + 512 * k) & 63;
    bias4[k] = isV ? reinterpret_cast<const float4*>(bv)[(ncol0 >> 2) + c4]
                   : make_float4(0.f, 0.f, 0.f, 0.f);
  }

  #pragma unroll
  for (int p = 0; p < 4; ++p) {
    if (wr == (p >> 1)) {
      const int mfb = (p & 1) * 2;
      #pragma unroll
      for (int mm = 0; mm < 2; ++mm)
        #pragma unroll
        for (int nf = 0; nf < 4; ++nf)
          #pragma unroll
          for (int r = 0; r < 4; ++r)
            ep[mm * 16 + (lane >> 4) * 4 + r][wc * 64 + nf * 16 + (lane & 15)] =
                acc[mfb + mm][nf][r];
    }
    __syncthreads();
    #pragma unroll
    for (int k = 0; k < 4; ++k) {
      int idx = tid + 512 * k;
      int row = idx >> 6;
      int c4  = idx & 63;
      long grow = m0 + p * 32 + row;
      float4 v = *reinterpret_cast<const float4*>(&ep[row][c4 * 4]);
      v.x += bias4[k].x; v.y += bias4[k].y; v.z += bias4[k].z; v.w += bias4[k].w;
      *reinterpret_cast<float4*>(&Co[grow * D_MODEL + ncol0 + c4 * 4]) = v;
      if (wbf) {
        u16 u[4] = { f2b(v.x), f2b(v.y), f2b(v.z), f2b(v.w) };
        *reinterpret_cast<uint2*>(&Cb[grow * D_MODEL + ncol0 + c4 * 4]) =
            *reinterpret_cast<const uint2*>(u);
      }
    }
    __syncthreads();
  }
}

// ---------------- attention pass 1 (fp32 K/V, R10-proven fallback) ----------------
__global__ __launch_bounds__(256) void attn_part(const float* __restrict__ qs,
                                                 const float* __restrict__ K,
                                                 const float* __restrict__ V,
                                                 float* __restrict__ part) {
  const int b = blockIdx.x >> 4;
  const int c = blockIdx.x & 15;
  const int tid = threadIdx.x;
  const int h = tid >> 4;
  const int j = tid & 15;
  const int s0 = (c * SEQ) >> 4;
  const int s1 = (((c + 1) * SEQ) >> 4);

  const float4 q4 = ((const float4*)(qs + (size_t)b * D_MODEL))[tid];
  float m = -1e30f, l = 0.f;
  float4 pv = make_float4(0.f, 0.f, 0.f, 0.f);

  int i = s0;
  for (; i + 2 <= s1; i += 2) {
    const float4 kA = ((const float4*)(K + (size_t)(b * SEQ + i) * D_MODEL))[tid];
    const float4 vA = ((const float4*)(V + (size_t)(b * SEQ + i) * D_MODEL))[tid];
    const float4 kB = ((const float4*)(K + (size_t)(b * SEQ + i + 1) * D_MODEL))[tid];
    const float4 vB = ((const float4*)(V + (size_t)(b * SEQ + i + 1) * D_MODEL))[tid];

    float sA = kA.x * q4.x + kA.y * q4.y + kA.z * q4.z + kA.w * q4.w;
    sA += __shfl_xor(sA, 1); sA += __shfl_xor(sA, 2);
    sA += __shfl_xor(sA, 4); sA += __shfl_xor(sA, 8);
    float mn = fmaxf(m, sA);
    float sc = __expf(m - mn);
    float p  = __expf(sA - mn);
    m = mn;
    l = l * sc + p;
    pv.x = pv.x * sc + p * vA.x; pv.y = pv.y * sc + p * vA.y;
    pv.z = pv.z * sc + p * vA.z; pv.w = pv.w * sc + p * vA.w;

    float sB = kB.x * q4.x + kB.y * q4.y + kB.z * q4.z + kB.w * q4.w;
    sB += __shfl_xor(sB, 1); sB += __shfl_xor(sB, 2);
    sB += __shfl_xor(sB, 4); sB += __shfl_xor(sB, 8);
    mn = fmaxf(m, sB);
    sc = __expf(m - mn);
    p  = __expf(sB - mn);
    m = mn;
    l = l * sc + p;
    pv.x = pv.x * sc + p * vB.x; pv.y = pv.y * sc + p * vB.y;
    pv.z = pv.z * sc + p * vB.z; pv.w = pv.w * sc + p * vB.w;
  }
  if (i < s1) {
    const float4 kA = ((const float4*)(K + (size_t)(b * SEQ + i) * D_MODEL))[tid];
    const float4 vA = ((const float4*)(V + (size_t)(b * SEQ + i) * D_MODEL))[tid];
    float sA = kA.x * q4.x + kA.y * q4.y + kA.z * q4.z + kA.w * q4.w;
    sA += __shfl_xor(sA, 1); sA += __shfl_xor(sA, 2);
    sA += __shfl_xor(sA, 4); sA += __shfl_xor(sA, 8);
    float mn = fmaxf(m, sA);
    float sc = __expf(m - mn);
    float p  = __expf(sA - mn);
    m = mn;
    l = l * sc + p;
    pv.x = pv.x * sc + p * vA.x; pv.y = pv.y * sc + p * vA.y;
    pv.z = pv.z * sc + p * vA.z; pv.w = pv.w * sc + p * vA.w;
  }

  float* pp = part + ((size_t)(b * NH + h) * NCH + c) * PSTR;
  *(float4*)(pp + j * 4) = pv;
  if (j == 0) { pp[64] = m; pp[65] = l; }
}

// ---------------- attention pass 1, bf16 K/V (half the read traffic) ----------------
__global__ __launch_bounds__(256) void attn_part_bf16(const float* __restrict__ qs,
                                                      const u16* __restrict__ Kb,
                                                      const u16* __restrict__ Vb,
                                                      float* __restrict__ part) {
  const int b = blockIdx.x >> 4;
  const int c = blockIdx.x & 15;
  const int tid = threadIdx.x;
  const int h = tid >> 4;
  const int j = tid & 15;
  const int s0 = (c * SEQ) >> 4;
  const int s1 = (((c + 1) * SEQ) >> 4);

  const float4 q4 = ((const float4*)(qs + (size_t)b * D_MODEL))[tid];
  float m = -1e30f, l = 0.f;
  float4 pv = make_float4(0.f, 0.f, 0.f, 0.f);

  int i = s0;
  for (; i + 2 <= s1; i += 2) {
    const ushort4 ka = ((const ushort4*)(Kb + (size_t)(b * SEQ + i) * D_MODEL))[tid];
    const ushort4 va = ((const ushort4*)(Vb + (size_t)(b * SEQ + i) * D_MODEL))[tid];
    const ushort4 kb = ((const ushort4*)(Kb + (size_t)(b * SEQ + i + 1) * D_MODEL))[tid];
    const ushort4 vb = ((const ushort4*)(Vb + (size_t)(b * SEQ + i + 1) * D_MODEL))[tid];

    float sA = b2f(ka.x) * q4.x + b2f(ka.y) * q4.y + b2f(ka.z) * q4.z + b2f(ka.w) * q4.w;
    sA += __shfl_xor(sA, 1); sA += __shfl_xor(sA, 2);
    sA += __shfl_xor(sA, 4); sA += __shfl_xor(sA, 8);
    float mn = fmaxf(m, sA);
    float sc = __expf(m - mn);
    float p  = __expf(sA - mn);
    m = mn;
    l = l * sc + p;
    pv.x = pv.x * sc + p * b2f(va.x); pv.y = pv.y * sc + p * b2f(va.y);
    pv.z = pv.z * sc + p * b2f(va.z); pv.w = pv.w * sc + p * b2f(va.w);

    float sB = b2f(kb.x) * q4.x + b2f(kb.y) * q4.y + b2f(kb.z) * q4.z + b2f(kb.w) * q4.w;
    sB += __shfl_xor(sB, 1); sB += __shfl_xor(sB, 2);
    sB += __shfl_xor(sB, 4); sB += __shfl_xor(sB, 8);
    mn = fmaxf(m, sB);
    sc = __expf(m - mn);
    p  = __expf(sB - mn);
    m = mn;
    l = l * sc + p;
    pv.x = pv.x * sc + p * b2f(vb.x); pv.y = pv.y * sc + p * b2f(vb.y);
    pv.z = pv.z * sc + p * b2f(vb.z); pv.w = pv.w * sc + p * b2f(vb.w);
  }
  if (i < s1) {
    const ushort4 ka = ((const ushort4*)(Kb + (size_t)(b * SEQ + i) * D_MODEL))[tid];
    const ushort4 va = ((const ushort4*)(Vb + (size_t)(b * SEQ + i) * D_MODEL))[tid];
    float sA = b2f(ka.x) * q4.x + b2f(ka.y) * q4.y + b2f(ka.z) * q4.z + b2f(ka.w) * q4.w;
    sA += __shfl_xor(sA, 1); sA += __shfl_xor(sA, 2);
    sA += __shfl_xor(sA, 4); sA += __shfl_xor(sA, 8);
    float mn = fmaxf(m, sA);
    float sc = __expf(m - mn);
    float p  = __expf(sA - mn);
    m = mn;
    l = l * sc + p;
    pv.x = pv.x * sc + p * b2f(va.x); pv.y = pv.y * sc + p * b2f(va.y);
    pv.z = pv.z * sc + p * b2f(va.z); pv.w = pv.w * sc + p * b2f(va.w);
  }

  float* pp = part + ((size_t)(b * NH + h) * NCH + c) * PSTR;
  *(float4*)(pp + j * 4) = pv;
  if (j == 0) { pp[64] = m; pp[65] = l; }
}

// ---------------- o-projection with fused 16-way chunk-combine (R10-proven) ----------------
__global__ __launch_bounds__(256) void oproj_comb(const float* __restrict__ part,
                                                  const float* __restrict__ Wo,
                                                  const float* __restrict__ bo,
                                                  float* __restrict__ out) {
  const int b = blockIdx.x >> 3, ch = blockIdx.x & 7;
  const int tid = threadIdx.x;
  __shared__ float xs[D_MODEL];

  {
    const int h = tid >> 4;
    const int d = (tid & 15) * 4;
    const float* pp = part + (size_t)(b * NH + h) * NCH * PSTR;
    float M = -1e30f;
    #pragma unroll
    for (int cc = 0; cc < NCH; ++cc) M = fmaxf(M, pp[cc * PSTR + 64]);
    float Lsum = 0.f;
    float4 o = make_float4(0.f, 0.f, 0.f, 0.f);
    #pragma unroll
    for (int cc = 0; cc < NCH; ++cc) {
      const float wgt = __expf(pp[cc * PSTR + 64] - M);
      Lsum += pp[cc * PSTR + 65] * wgt;
      float4 pv = *(const float4*)(pp + cc * PSTR + d);
      o.x += pv.x * wgt; o.y += pv.y * wgt; o.z += pv.z * wgt; o.w += pv.w * wgt;
    }
    const float inv = 1.0f / Lsum;
    xs[h * HD + d]     = o.x * inv;
    xs[h * HD + d + 1] = o.y * inv;
    xs[h * HD + d + 2] = o.z * inv;
    xs[h * HD + d + 3] = o.w * inv;
  }
  __syncthreads();

  const int n = ch * 128 + (tid >> 1);
  const int half = tid & 1;
  const float4* wp = (const float4*)(Wo + (size_t)n * D_MODEL + half * 512);
  const float4* xp = (const float4*)xs + half * 128;
  float a = 0.f;
  #pragma unroll 8
  for (int i = 0; i < 128; ++i) {
    float4 w = wp[i], xv = xp[i];
    a += w.x * xv.x + w.y * xv.y + w.z * xv.z + w.w * xv.w;
  }
  a += __shfl_xor(a, 1);
  if (!half) out[(size_t)b * D_MODEL + n] = a + bo[n];
}

// ---------------- launch ----------------
extern "C" void kernel_launch(void* const* d_in, const int* in_sizes, int n_in,
                              void* d_out, int out_size, void* d_ws, size_t ws_size,
                              hipStream_t stream) {
  const float* hs  = (const float*)d_in[0];
  const float* enc = (const float*)d_in[1];
  const float* Wq  = (const float*)d_in[2];
  const float* bq  = (const float*)d_in[3];
  const float* Wk  = (const float*)d_in[4];
  const float* Wv  = (const float*)d_in[5];
  const float* bv  = (const float*)d_in[6];
  const float* Wo  = (const float*)d_in[7];
  const float* bo  = (const float*)d_in[8];

  float* out   = (float*)d_out;
  float* attnO = out;
  float* Kout  = out + 32768;
  float* Vout  = Kout + (size_t)MROWS * D_MODEL;

  char* ws = (char*)d_ws;
  const size_t off_wkvb = (size_t)MROWS * D_MODEL * 2;        // 98,304,000
  const size_t off_qs   = off_wkvb + 4194304;
  const size_t off_part = off_qs + 131072;
  const size_t off_kb   = off_part + 2228224;
  const size_t off_vb   = off_kb + (size_t)MROWS * D_MODEL * 2;
  const size_t need     = off_vb + (size_t)MROWS * D_MODEL * 2;  // ~302 MB

  u16*   encb = (u16*)ws;
  u16*   wkvb = (u16*)(ws + off_wkvb);
  float* qs   = (float*)(ws + off_qs);
  float* part = (float*)(ws + off_part);
  u16*   Kb   = (u16*)(ws + off_kb);
  u16*   Vb   = (u16*)(ws + off_vb);

  const bool bf = (ws_size >= need);

  cast_all_q<<<ENC_BLOCKS + W_BLOCKS + QPROJ_BLOCKS, 256, 0, stream>>>(enc, Wk, Wv, hs, Wq, bq,
                                                                       encb, wkvb, qs);

  gemm_kv<<<(MROWS / GBM) * (2048 / GBN), 512, 0, stream>>>(encb, wkvb, bv, Kout, Vout,
                                                            Kb, Vb, bf ? 1 : 0);

  if (bf) attn_part_bf16<<<B_SZ * NCH, 256, 0, stream>>>(qs, Kb, Vb, part);
  else    attn_part<<<B_SZ * NCH, 256, 0, stream>>>(qs, Kout, Vout, part);
  oproj_comb<<<B_SZ * 8, 256, 0, stream>>>(part, Wo, bo, attnO);
}

// Round 16
// 442.093 us; speedup vs baseline: 1.0319x; 1.0319x over previous
//
#include <hip/hip_runtime.h>
#include <cstdint>
#include <cstddef>

#define D_MODEL 1024
#define NH      16
#define HD      64
#define B_SZ    32
#define SEQ     1500
#define MROWS   (B_SZ * SEQ)   // 48000
#define KD      1024
#define NCH     16             // s-chunks per batch (R10-proven)
#define PSTR    68             // part stride: pv[64], m, l, pad2

typedef __attribute__((ext_vector_type(8))) short bf16x8;
typedef __attribute__((ext_vector_type(4))) float f32x4;
typedef unsigned short u16;

__device__ __forceinline__ u16 f2b(float f) {
  unsigned int x = __float_as_uint(f);
  x = (x + 0x7FFFu + ((x >> 16) & 1u)) >> 16;   // RNE
  return (u16)x;
}

// ---------------- cast + q-proj, role-split by block range ----------------
// enc: 3000 blocks x 256 thr x 16 float4 = 12,288,000 float4 (exact cover)
// W:     64 blocks x 256 thr x 32 float4 =    524,288 float4 (Wk then Wv)
// qproj: 64 blocks
#define ENC_BLOCKS 3000
#define W_BLOCKS   64
#define QPROJ_BLOCKS 64

__global__ __launch_bounds__(256) void cast_all_q(const float* __restrict__ enc,
                                                  const float* __restrict__ Wk,
                                                  const float* __restrict__ Wv,
                                                  const float* __restrict__ hs,
                                                  const float* __restrict__ Wq,
                                                  const float* __restrict__ bq,
                                                  u16* __restrict__ encb,
                                                  u16* __restrict__ wkvb,
                                                  float* __restrict__ qs) {
  const int tid = threadIdx.x;
  const int bid = blockIdx.x;
  if (bid < ENC_BLOCKS) {
    const float4* s4 = (const float4*)enc;
    const size_t base = (size_t)bid * 256 + tid;
    #pragma unroll
    for (int k = 0; k < 16; ++k) {
      size_t i = base + (size_t)k * (ENC_BLOCKS * 256);
      float4 a = s4[i];
      u16 u[4] = { f2b(a.x), f2b(a.y), f2b(a.z), f2b(a.w) };
      *reinterpret_cast<uint2*>(encb + i * 4) = *reinterpret_cast<const uint2*>(u);
    }
  } else if (bid < ENC_BLOCKS + W_BLOCKS) {
    const int wb = bid - ENC_BLOCKS;
    const size_t base = (size_t)wb * 256 + tid;
    const int NW4 = KD * KD / 4;           // 262,144 float4 per weight
    #pragma unroll
    for (int k = 0; k < 32; ++k) {
      size_t i = base + (size_t)k * (W_BLOCKS * 256);
      const float4* s4 = (i < (size_t)NW4) ? (const float4*)Wk : (const float4*)Wv;
      size_t j = (i < (size_t)NW4) ? i : i - NW4;
      float4 a = s4[j];
      u16 u[4] = { f2b(a.x), f2b(a.y), f2b(a.z), f2b(a.w) };
      *reinterpret_cast<uint2*>(wkvb + i * 4) = *reinterpret_cast<const uint2*>(u);
    }
  } else {
    // q-proj: block qb covers Wq rows [qb*16, qb*16+16) for all 32 batches
    const int qb = bid - ENC_BLOCKS - W_BLOCKS;
    const int n  = qb * 16 + (tid & 15);
    const int bb = tid >> 4;
    const float4* wp  = (const float4*)(Wq + (size_t)n * D_MODEL);
    const float4* x0p = (const float4*)(hs + (size_t)bb * D_MODEL);
    const float4* x1p = (const float4*)(hs + (size_t)(bb + 16) * D_MODEL);
    float a0 = 0.f, a1 = 0.f;
    #pragma unroll 8
    for (int i = 0; i < D_MODEL / 4; ++i) {
      float4 w = wp[i], x0 = x0p[i], x1 = x1p[i];
      a0 += w.x * x0.x + w.y * x0.y + w.z * x0.z + w.w * x0.w;
      a1 += w.x * x1.x + w.y * x1.y + w.z * x1.z + w.w * x1.w;
    }
    const float bqn = bq[n];
    qs[(size_t)bb * D_MODEL + n]        = (a0 + bqn) * 0.125f;   // SCALE^2 folded
    qs[(size_t)(bb + 16) * D_MODEL + n] = (a1 + bqn) * 0.125f;
  }
}

// ================= 128x256 bf16 MFMA GEMM, triple-buffered (depth-3 prefetch) =================
#define GBM 128
#define GBN 256
#define GBK 32
#define GNT (KD / GBK)   // 32 K-tiles
#define AT  (GBM * GBK)  // 4096 u16 = 8 KB
#define BT  (GBN * GBK)  // 8192 u16 = 16 KB

__device__ __forceinline__ void stageA(const u16* __restrict__ Ag, u16* lbuf,
                                       long m0, int kt, int tid) {
  int c = tid;
  int r = c >> 2, cp = c & 3;
  int scp = cp ^ ((r >> 1) & 3);
  const u16* src = Ag + (m0 + r) * (long)KD + kt * GBK + scp * 8;
  __builtin_amdgcn_global_load_lds((const __attribute__((address_space(1))) void*)src,
      (__attribute__((address_space(3))) void*)(lbuf + (size_t)c * 8), 16, 0, 0);
}

__device__ __forceinline__ void stageB(const u16* __restrict__ Bg, u16* lbuf,
                                       int n0, int kt, int tid) {
  #pragma unroll
  for (int L = 0; L < 2; ++L) {
    int c = tid + L * 512;
    int r = c >> 2, cp = c & 3;
    int scp = cp ^ ((r >> 1) & 3);
    const u16* src = Bg + (size_t)(n0 + r) * KD + kt * GBK + scp * 8;
    __builtin_amdgcn_global_load_lds((const __attribute__((address_space(1))) void*)src,
        (__attribute__((address_space(3))) void*)(lbuf + (size_t)c * 8), 16, 0, 0);
  }
}

__device__ __forceinline__ bf16x8 ldFrag(const u16* buf, int row, int lane) {
  int r  = row + (lane & 15);
  int ch = (lane >> 4) ^ ((r >> 1) & 3);
  return *(const bf16x8*)(buf + (size_t)r * GBK + ch * 8);
}

__global__ __launch_bounds__(512, 4) void gemm_kv(const u16* __restrict__ A,
                                                  const u16* __restrict__ Bm,
                                                  const float* __restrict__ bv,
                                                  float* __restrict__ Kout,
                                                  float* __restrict__ Vout) {
  __shared__ __align__(16) char smem[3 * (GBM + GBN) * GBK * 2];   // 72 KiB
  u16* sAb = (u16*)smem;                 // 3 x 8 KB
  u16* sBb = sAb + 3 * AT;               // 3 x 16 KB

  const int tid  = threadIdx.x;
  const int lane = tid & 63;
  const int wid  = tid >> 6;
  const int wr   = wid >> 2;
  const int wc   = wid & 3;

  int bx = (blockIdx.x & 7) * (gridDim.x >> 3) + (blockIdx.x >> 3);
  const int  mt = bx >> 3;
  const int  nt = bx & 7;
  const long m0 = (long)mt * GBM;
  const int  n0 = nt * GBN;

  // prologue: tiles 0,1,2 (3 loads/thread each, in tile order)
  stageA(A, sAb + 0 * AT, m0, 0, tid);
  stageB(Bm, sBb + 0 * BT, n0, 0, tid);
  stageA(A, sAb + 1 * AT, m0, 1, tid);
  stageB(Bm, sBb + 1 * BT, n0, 1, tid);
  stageA(A, sAb + 2 * AT, m0, 2, tid);
  stageB(Bm, sBb + 2 * BT, n0, 2, tid);

  f32x4 acc[4][4] = {};

  for (int t = 0; t < GNT; ++t) {
    // steady state: tiles t+1, t+2 in flight (6 loads/thread)
    if (t < GNT - 2)       { asm volatile("s_waitcnt vmcnt(6)" ::: "memory"); }
    else if (t == GNT - 2) { asm volatile("s_waitcnt vmcnt(3)" ::: "memory"); }
    else                   { asm volatile("s_waitcnt vmcnt(0)" ::: "memory"); }
    __builtin_amdgcn_s_barrier();

    const int  bi = t % 3;
    const u16* cA = sAb + bi * AT;
    const u16* cB = sBb + bi * BT;
    bf16x8 af[4], bfr[4];
    #pragma unroll
    for (int mf = 0; mf < 4; ++mf) af[mf]  = ldFrag(cA, wr * 64 + mf * 16, lane);
    #pragma unroll
    for (int nf = 0; nf < 4; ++nf) bfr[nf] = ldFrag(cB, wc * 64 + nf * 16, lane);
    asm volatile("s_waitcnt lgkmcnt(0)" ::: "memory");
    __builtin_amdgcn_s_barrier();

    // prefetch tile t+3 into the buffer just consumed
    if (t + 3 < GNT) {
      stageA(A, sAb + bi * AT, m0, t + 3, tid);
      stageB(Bm, sBb + bi * BT, n0, t + 3, tid);
    }

    #pragma unroll
    for (int mf = 0; mf < 4; ++mf)
      #pragma unroll
      for (int nf = 0; nf < 4; ++nf)
        acc[mf][nf] = __builtin_amdgcn_mfma_f32_16x16x32_bf16(af[mf], bfr[nf], acc[mf][nf], 0, 0, 0);
  }

  // ---- coalesced epilogue via LDS transpose ([32][260] f32 slabs) ----
  __syncthreads();
  float (*ep)[260] = (float(*)[260])smem;

  const bool isV = (nt >= 4);
  float* Co = isV ? Vout : Kout;
  const int ncol0 = isV ? (n0 - 1024) : n0;
  float4 bias4[4];
  #pragma unroll
  for (int k = 0; k < 4; ++k) {
    int c4 = (tid + 512 * k) & 63;
    bias4[k] = isV ? reinterpret_cast<const float4*>(bv)[(ncol0 >> 2) + c4]
                   : make_float4(0.f, 0.f, 0.f, 0.f);
  }

  #pragma unroll
  for (int p = 0; p < 4; ++p) {
    if (wr == (p >> 1)) {
      const int mfb = (p & 1) * 2;
      #pragma unroll
      for (int mm = 0; mm < 2; ++mm)
        #pragma unroll
        for (int nf = 0; nf < 4; ++nf)
          #pragma unroll
          for (int r = 0; r < 4; ++r)
            ep[mm * 16 + (lane >> 4) * 4 + r][wc * 64 + nf * 16 + (lane & 15)] =
                acc[mfb + mm][nf][r];
    }
    __syncthreads();
    #pragma unroll
    for (int k = 0; k < 4; ++k) {
      int idx = tid + 512 * k;
      int row = idx >> 6;
      int c4  = idx & 63;
      long grow = m0 + p * 32 + row;
      float4 v = *reinterpret_cast<const float4*>(&ep[row][c4 * 4]);
      v.x += bias4[k].x; v.y += bias4[k].y; v.z += bias4[k].z; v.w += bias4[k].w;
      *reinterpret_cast<float4*>(&Co[grow * D_MODEL + ncol0 + c4 * 4]) = v;
    }
    __syncthreads();
  }
}

// ---------------- attention pass 1: full-row streaming, all 16 heads per block ----------------
__global__ __launch_bounds__(256) void attn_part(const float* __restrict__ qs,
                                                 const float* __restrict__ K,
                                                 const float* __restrict__ V,
                                                 float* __restrict__ part) {
  const int b = blockIdx.x >> 4;
  const int c = blockIdx.x & 15;
  const int tid = threadIdx.x;
  const int h = tid >> 4;
  const int j = tid & 15;
  const int s0 = (c * SEQ) >> 4;
  const int s1 = (((c + 1) * SEQ) >> 4);

  const float4 q4 = ((const float4*)(qs + (size_t)b * D_MODEL))[tid];
  float m = -1e30f, l = 0.f;
  float4 pv = make_float4(0.f, 0.f, 0.f, 0.f);

  int i = s0;
  for (; i + 2 <= s1; i += 2) {
    const float4 kA = ((const float4*)(K + (size_t)(b * SEQ + i) * D_MODEL))[tid];
    const float4 vA = ((const float4*)(V + (size_t)(b * SEQ + i) * D_MODEL))[tid];
    const float4 kB = ((const float4*)(K + (size_t)(b * SEQ + i + 1) * D_MODEL))[tid];
    const float4 vB = ((const float4*)(V + (size_t)(b * SEQ + i + 1) * D_MODEL))[tid];

    float sA = kA.x * q4.x + kA.y * q4.y + kA.z * q4.z + kA.w * q4.w;
    sA += __shfl_xor(sA, 1); sA += __shfl_xor(sA, 2);
    sA += __shfl_xor(sA, 4); sA += __shfl_xor(sA, 8);
    float mn = fmaxf(m, sA);
    float sc = __expf(m - mn);
    float p  = __expf(sA - mn);
    m = mn;
    l = l * sc + p;
    pv.x = pv.x * sc + p * vA.x; pv.y = pv.y * sc + p * vA.y;
    pv.z = pv.z * sc + p * vA.z; pv.w = pv.w * sc + p * vA.w;

    float sB = kB.x * q4.x + kB.y * q4.y + kB.z * q4.z + kB.w * q4.w;
    sB += __shfl_xor(sB, 1); sB += __shfl_xor(sB, 2);
    sB += __shfl_xor(sB, 4); sB += __shfl_xor(sB, 8);
    mn = fmaxf(m, sB);
    sc = __expf(m - mn);
    p  = __expf(sB - mn);
    m = mn;
    l = l * sc + p;
    pv.x = pv.x * sc + p * vB.x; pv.y = pv.y * sc + p * vB.y;
    pv.z = pv.z * sc + p * vB.z; pv.w = pv.w * sc + p * vB.w;
  }
  if (i < s1) {
    const float4 kA = ((const float4*)(K + (size_t)(b * SEQ + i) * D_MODEL))[tid];
    const float4 vA = ((const float4*)(V + (size_t)(b * SEQ + i) * D_MODEL))[tid];
    float sA = kA.x * q4.x + kA.y * q4.y + kA.z * q4.z + kA.w * q4.w;
    sA += __shfl_xor(sA, 1); sA += __shfl_xor(sA, 2);
    sA += __shfl_xor(sA, 4); sA += __shfl_xor(sA, 8);
    float mn = fmaxf(m, sA);
    float sc = __expf(m - mn);
    float p  = __expf(sA - mn);
    m = mn;
    l = l * sc + p;
    pv.x = pv.x * sc + p * vA.x; pv.y = pv.y * sc + p * vA.y;
    pv.z = pv.z * sc + p * vA.z; pv.w = pv.w * sc + p * vA.w;
  }

  float* pp = part + ((size_t)(b * NH + h) * NCH + c) * PSTR;
  *(float4*)(pp + j * 4) = pv;
  if (j == 0) { pp[64] = m; pp[65] = l; }
}

// ---------------- o-projection with fused 16-way chunk-combine: 8 blocks per batch ----------------
__global__ __launch_bounds__(256) void oproj_comb(const float* __restrict__ part,
                                                  const float* __restrict__ Wo,
                                                  const float* __restrict__ bo,
                                                  float* __restrict__ out) {
  const int b = blockIdx.x >> 3, ch = blockIdx.x & 7;
  const int tid = threadIdx.x;
  __shared__ float xs[D_MODEL];

  {
    const int h = tid >> 4;
    const int d = (tid & 15) * 4;
    const float* pp = part + (size_t)(b * NH + h) * NCH * PSTR;
    float M = -1e30f;
    #pragma unroll
    for (int cc = 0; cc < NCH; ++cc) M = fmaxf(M, pp[cc * PSTR + 64]);
    float Lsum = 0.f;
    float4 o = make_float4(0.f, 0.f, 0.f, 0.f);
    #pragma unroll
    for (int cc = 0; cc < NCH; ++cc) {
      const float wgt = __expf(pp[cc * PSTR + 64] - M);
      Lsum += pp[cc * PSTR + 65] * wgt;
      float4 pv = *(const float4*)(pp + cc * PSTR + d);
      o.x += pv.x * wgt; o.y += pv.y * wgt; o.z += pv.z * wgt; o.w += pv.w * wgt;
    }
    const float inv = 1.0f / Lsum;
    xs[h * HD + d]     = o.x * inv;
    xs[h * HD + d + 1] = o.y * inv;
    xs[h * HD + d + 2] = o.z * inv;
    xs[h * HD + d + 3] = o.w * inv;
  }
  __syncthreads();

  const int n = ch * 128 + (tid >> 1);
  const int half = tid & 1;
  const float4* wp = (const float4*)(Wo + (size_t)n * D_MODEL + half * 512);
  const float4* xp = (const float4*)xs + half * 128;
  float a = 0.f;
  #pragma unroll 8
  for (int i = 0; i < 128; ++i) {
    float4 w = wp[i], xv = xp[i];
    a += w.x * xv.x + w.y * xv.y + w.z * xv.z + w.w * xv.w;
  }
  a += __shfl_xor(a, 1);
  if (!half) out[(size_t)b * D_MODEL + n] = a + bo[n];
}

// ---------------- launch ----------------
extern "C" void kernel_launch(void* const* d_in, const int* in_sizes, int n_in,
                              void* d_out, int out_size, void* d_ws, size_t ws_size,
                              hipStream_t stream) {
  const float* hs  = (const float*)d_in[0];
  const float* enc = (const float*)d_in[1];
  const float* Wq  = (const float*)d_in[2];
  const float* bq  = (const float*)d_in[3];
  const float* Wk  = (const float*)d_in[4];
  const float* Wv  = (const float*)d_in[5];
  const float* bv  = (const float*)d_in[6];
  const float* Wo  = (const float*)d_in[7];
  const float* bo  = (const float*)d_in[8];

  float* out   = (float*)d_out;
  float* attnO = out;
  float* Kout  = out + 32768;
  float* Vout  = Kout + (size_t)MROWS * D_MODEL;

  char* ws = (char*)d_ws;
  const size_t off_wkvb = (size_t)MROWS * D_MODEL * 2;        // 98,304,000
  const size_t off_qs   = off_wkvb + 4194304;
  const size_t off_part = off_qs + 131072;                    // 512*16*68*4 = 2,228,224 B

  u16*   encb = (u16*)ws;
  u16*   wkvb = (u16*)(ws + off_wkvb);
  float* qs   = (float*)(ws + off_qs);
  float* part = (float*)(ws + off_part);

  cast_all_q<<<ENC_BLOCKS + W_BLOCKS + QPROJ_BLOCKS, 256, 0, stream>>>(enc, Wk, Wv, hs, Wq, bq,
                                                                       encb, wkvb, qs);

  gemm_kv<<<(MROWS / GBM) * (2048 / GBN), 512, 0, stream>>>(encb, wkvb, bv, Kout, Vout);

  attn_part<<<B_SZ * NCH, 256, 0, stream>>>(qs, Kout, Vout, part);
  oproj_comb<<<B_SZ * 8, 256, 0, stream>>>(part, Wo, bo, attnO);
}

// Round 17
// 439.549 us; speedup vs baseline: 1.0378x; 1.0058x over previous
//
#include <hip/hip_runtime.h>
#include <cstdint>
#include <cstddef>

#define D_MODEL 1024
#define NH      16
#define HD      64
#define B_SZ    32
#define SEQ     1500
#define MROWS   (B_SZ * SEQ)   // 48000
#define KD      1024
#define NCH     16             // s-chunks per batch (R10-proven)
#define PSTR    68             // part stride: pv[64], m, l, pad2

typedef __attribute__((ext_vector_type(8))) short bf16x8;
typedef __attribute__((ext_vector_type(4))) float f32x4;
typedef unsigned short u16;

__device__ __forceinline__ u16 f2b(float f) {
  unsigned int x = __float_as_uint(f);
  x = (x + 0x7FFFu + ((x >> 16) & 1u)) >> 16;   // RNE
  return (u16)x;
}

// ---------------- cast + q-proj, role-split by block range (R10-proven) ----------------
#define ENC_BLOCKS 3000
#define W_BLOCKS   64
#define QPROJ_BLOCKS 64

__global__ __launch_bounds__(256) void cast_all_q(const float* __restrict__ enc,
                                                  const float* __restrict__ Wk,
                                                  const float* __restrict__ Wv,
                                                  const float* __restrict__ hs,
                                                  const float* __restrict__ Wq,
                                                  const float* __restrict__ bq,
                                                  u16* __restrict__ encb,
                                                  u16* __restrict__ wkvb,
                                                  float* __restrict__ qs) {
  const int tid = threadIdx.x;
  const int bid = blockIdx.x;
  if (bid < ENC_BLOCKS) {
    const float4* s4 = (const float4*)enc;
    const size_t base = (size_t)bid * 256 + tid;
    #pragma unroll
    for (int k = 0; k < 16; ++k) {
      size_t i = base + (size_t)k * (ENC_BLOCKS * 256);
      float4 a = s4[i];
      u16 u[4] = { f2b(a.x), f2b(a.y), f2b(a.z), f2b(a.w) };
      *reinterpret_cast<uint2*>(encb + i * 4) = *reinterpret_cast<const uint2*>(u);
    }
  } else if (bid < ENC_BLOCKS + W_BLOCKS) {
    const int wb = bid - ENC_BLOCKS;
    const size_t base = (size_t)wb * 256 + tid;
    const int NW4 = KD * KD / 4;           // 262,144 float4 per weight
    #pragma unroll
    for (int k = 0; k < 32; ++k) {
      size_t i = base + (size_t)k * (W_BLOCKS * 256);
      const float4* s4 = (i < (size_t)NW4) ? (const float4*)Wk : (const float4*)Wv;
      size_t j = (i < (size_t)NW4) ? i : i - NW4;
      float4 a = s4[j];
      u16 u[4] = { f2b(a.x), f2b(a.y), f2b(a.z), f2b(a.w) };
      *reinterpret_cast<uint2*>(wkvb + i * 4) = *reinterpret_cast<const uint2*>(u);
    }
  } else {
    const int qb = bid - ENC_BLOCKS - W_BLOCKS;
    const int n  = qb * 16 + (tid & 15);
    const int bb = tid >> 4;
    const float4* wp  = (const float4*)(Wq + (size_t)n * D_MODEL);
    const float4* x0p = (const float4*)(hs + (size_t)bb * D_MODEL);
    const float4* x1p = (const float4*)(hs + (size_t)(bb + 16) * D_MODEL);
    float a0 = 0.f, a1 = 0.f;
    #pragma unroll 8
    for (int i = 0; i < D_MODEL / 4; ++i) {
      float4 w = wp[i], x0 = x0p[i], x1 = x1p[i];
      a0 += w.x * x0.x + w.y * x0.y + w.z * x0.z + w.w * x0.w;
      a1 += w.x * x1.x + w.y * x1.y + w.z * x1.z + w.w * x1.w;
    }
    const float bqn = bq[n];
    qs[(size_t)bb * D_MODEL + n]        = (a0 + bqn) * 0.125f;   // SCALE^2 folded
    qs[(size_t)(bb + 16) * D_MODEL + n] = (a1 + bqn) * 0.125f;
  }
}

// ================= 128x256 bf16 MFMA GEMM, triple-buffered, 4 waves / 4x8 register blocking =================
// Same tile, same LDS geometry/swizzle/staging addresses as the R10-proven kernel.
// Change: 256 threads (2x2 wave grid, each wave 64x128 out, acc[4][8]) -> LDS frag-read
// traffic per FLOP drops 25% (12 reads feed 32 MFMAs vs 8 feeding 16).
#define GBM 128
#define GBN 256
#define GBK 32
#define GNT (KD / GBK)   // 32 K-tiles
#define AT  (GBM * GBK)  // 4096 u16 = 8 KB
#define BT  (GBN * GBK)  // 8192 u16 = 16 KB

__device__ __forceinline__ void stageA(const u16* __restrict__ Ag, u16* lbuf,
                                       long m0, int kt, int tid) {
  #pragma unroll
  for (int L = 0; L < 2; ++L) {
    int c = tid + L * 256;              // 512 chunks of 16B (128 rows x 4)
    int r = c >> 2, cp = c & 3;
    int scp = cp ^ ((r >> 1) & 3);
    const u16* src = Ag + (m0 + r) * (long)KD + kt * GBK + scp * 8;
    __builtin_amdgcn_global_load_lds((const __attribute__((address_space(1))) void*)src,
        (__attribute__((address_space(3))) void*)(lbuf + (size_t)c * 8), 16, 0, 0);
  }
}

__device__ __forceinline__ void stageB(const u16* __restrict__ Bg, u16* lbuf,
                                       int n0, int kt, int tid) {
  #pragma unroll
  for (int L = 0; L < 4; ++L) {
    int c = tid + L * 256;              // 1024 chunks (256 rows x 4)
    int r = c >> 2, cp = c & 3;
    int scp = cp ^ ((r >> 1) & 3);
    const u16* src = Bg + (size_t)(n0 + r) * KD + kt * GBK + scp * 8;
    __builtin_amdgcn_global_load_lds((const __attribute__((address_space(1))) void*)src,
        (__attribute__((address_space(3))) void*)(lbuf + (size_t)c * 8), 16, 0, 0);
  }
}

__device__ __forceinline__ bf16x8 ldFrag(const u16* buf, int row, int lane) {
  int r  = row + (lane & 15);
  int ch = (lane >> 4) ^ ((r >> 1) & 3);
  return *(const bf16x8*)(buf + (size_t)r * GBK + ch * 8);
}

__global__ __launch_bounds__(256, 2) void gemm_kv(const u16* __restrict__ A,
                                                  const u16* __restrict__ Bm,
                                                  const float* __restrict__ bv,
                                                  float* __restrict__ Kout,
                                                  float* __restrict__ Vout) {
  __shared__ __align__(16) char smem[3 * (GBM + GBN) * GBK * 2];   // 72 KiB
  u16* sAb = (u16*)smem;                 // 3 x 8 KB
  u16* sBb = sAb + 3 * AT;               // 3 x 16 KB

  const int tid  = threadIdx.x;
  const int lane = tid & 63;
  const int wid  = tid >> 6;             // 0..3
  const int wr   = wid >> 1;             // 0..1: 64-row half
  const int wc   = wid & 1;              // 0..1: 128-col half

  int bx = (blockIdx.x & 7) * (gridDim.x >> 3) + (blockIdx.x >> 3);
  const int  mt = bx >> 3;
  const int  nt = bx & 7;
  const long m0 = (long)mt * GBM;
  const int  n0 = nt * GBN;

  // prologue: tiles 0,1,2 (6 loads/thread each, in tile order)
  stageA(A, sAb + 0 * AT, m0, 0, tid);
  stageB(Bm, sBb + 0 * BT, n0, 0, tid);
  stageA(A, sAb + 1 * AT, m0, 1, tid);
  stageB(Bm, sBb + 1 * BT, n0, 1, tid);
  stageA(A, sAb + 2 * AT, m0, 2, tid);
  stageB(Bm, sBb + 2 * BT, n0, 2, tid);

  f32x4 acc[4][8] = {};

  for (int t = 0; t < GNT; ++t) {
    // steady state: tiles t+1, t+2 in flight (12 loads/thread)
    if (t < GNT - 2)       { asm volatile("s_waitcnt vmcnt(12)" ::: "memory"); }
    else if (t == GNT - 2) { asm volatile("s_waitcnt vmcnt(6)" ::: "memory"); }
    else                   { asm volatile("s_waitcnt vmcnt(0)" ::: "memory"); }
    __builtin_amdgcn_s_barrier();

    const int  bi = t % 3;
    const u16* cA = sAb + bi * AT;
    const u16* cB = sBb + bi * BT;
    bf16x8 af[4], bfr[8];
    #pragma unroll
    for (int mf = 0; mf < 4; ++mf) af[mf]  = ldFrag(cA, wr * 64 + mf * 16, lane);
    #pragma unroll
    for (int nf = 0; nf < 8; ++nf) bfr[nf] = ldFrag(cB, wc * 128 + nf * 16, lane);
    asm volatile("s_waitcnt lgkmcnt(0)" ::: "memory");
    __builtin_amdgcn_s_barrier();

    // prefetch tile t+3 into the buffer just consumed
    if (t + 3 < GNT) {
      stageA(A, sAb + bi * AT, m0, t + 3, tid);
      stageB(Bm, sBb + bi * BT, n0, t + 3, tid);
    }

    #pragma unroll
    for (int mf = 0; mf < 4; ++mf)
      #pragma unroll
      for (int nf = 0; nf < 8; ++nf)
        acc[mf][nf] = __builtin_amdgcn_mfma_f32_16x16x32_bf16(af[mf], bfr[nf], acc[mf][nf], 0, 0, 0);
  }

  // ---- coalesced epilogue via LDS transpose ([32][260] f32 slabs) ----
  __syncthreads();
  float (*ep)[260] = (float(*)[260])smem;

  const bool isV = (nt >= 4);
  float* Co = isV ? Vout : Kout;
  const int ncol0 = isV ? (n0 - 1024) : n0;
  const int c4b = tid & 63;   // (tid + 256k) & 63 is k-invariant
  const float4 bias1 = isV ? reinterpret_cast<const float4*>(bv)[(ncol0 >> 2) + c4b]
                           : make_float4(0.f, 0.f, 0.f, 0.f);

  #pragma unroll
  for (int p = 0; p < 4; ++p) {         // 32-row slabs of the 128-row block
    if (wr == (p >> 1)) {
      const int mfb = (p & 1) * 2;
      #pragma unroll
      for (int mm = 0; mm < 2; ++mm)
        #pragma unroll
        for (int nf = 0; nf < 8; ++nf)
          #pragma unroll
          for (int r = 0; r < 4; ++r)
            ep[mm * 16 + (lane >> 4) * 4 + r][wc * 128 + nf * 16 + (lane & 15)] =
                acc[mfb + mm][nf][r];
    }
    __syncthreads();
    #pragma unroll
    for (int k = 0; k < 8; ++k) {
      int idx = tid + 256 * k;          // 0..2047 float4s
      int row = idx >> 6;               // 0..31
      int c4  = idx & 63;
      long grow = m0 + p * 32 + row;
      float4 v = *reinterpret_cast<const float4*>(&ep[row][c4 * 4]);
      v.x += bias1.x; v.y += bias1.y; v.z += bias1.z; v.w += bias1.w;
      *reinterpret_cast<float4*>(&Co[grow * D_MODEL + ncol0 + c4 * 4]) = v;
    }
    __syncthreads();
  }
}

// ---------------- attention pass 1: full-row streaming, all 16 heads per block (R10-proven) ----------------
__global__ __launch_bounds__(256) void attn_part(const float* __restrict__ qs,
                                                 const float* __restrict__ K,
                                                 const float* __restrict__ V,
                                                 float* __restrict__ part) {
  const int b = blockIdx.x >> 4;
  const int c = blockIdx.x & 15;
  const int tid = threadIdx.x;
  const int h = tid >> 4;
  const int j = tid & 15;
  const int s0 = (c * SEQ) >> 4;
  const int s1 = (((c + 1) * SEQ) >> 4);

  const float4 q4 = ((const float4*)(qs + (size_t)b * D_MODEL))[tid];
  float m = -1e30f, l = 0.f;
  float4 pv = make_float4(0.f, 0.f, 0.f, 0.f);

  int i = s0;
  for (; i + 2 <= s1; i += 2) {
    const float4 kA = ((const float4*)(K + (size_t)(b * SEQ + i) * D_MODEL))[tid];
    const float4 vA = ((const float4*)(V + (size_t)(b * SEQ + i) * D_MODEL))[tid];
    const float4 kB = ((const float4*)(K + (size_t)(b * SEQ + i + 1) * D_MODEL))[tid];
    const float4 vB = ((const float4*)(V + (size_t)(b * SEQ + i + 1) * D_MODEL))[tid];

    float sA = kA.x * q4.x + kA.y * q4.y + kA.z * q4.z + kA.w * q4.w;
    sA += __shfl_xor(sA, 1); sA += __shfl_xor(sA, 2);
    sA += __shfl_xor(sA, 4); sA += __shfl_xor(sA, 8);
    float mn = fmaxf(m, sA);
    float sc = __expf(m - mn);
    float p  = __expf(sA - mn);
    m = mn;
    l = l * sc + p;
    pv.x = pv.x * sc + p * vA.x; pv.y = pv.y * sc + p * vA.y;
    pv.z = pv.z * sc + p * vA.z; pv.w = pv.w * sc + p * vA.w;

    float sB = kB.x * q4.x + kB.y * q4.y + kB.z * q4.z + kB.w * q4.w;
    sB += __shfl_xor(sB, 1); sB += __shfl_xor(sB, 2);
    sB += __shfl_xor(sB, 4); sB += __shfl_xor(sB, 8);
    mn = fmaxf(m, sB);
    sc = __expf(m - mn);
    p  = __expf(sB - mn);
    m = mn;
    l = l * sc + p;
    pv.x = pv.x * sc + p * vB.x; pv.y = pv.y * sc + p * vB.y;
    pv.z = pv.z * sc + p * vB.z; pv.w = pv.w * sc + p * vB.w;
  }
  if (i < s1) {
    const float4 kA = ((const float4*)(K + (size_t)(b * SEQ + i) * D_MODEL))[tid];
    const float4 vA = ((const float4*)(V + (size_t)(b * SEQ + i) * D_MODEL))[tid];
    float sA = kA.x * q4.x + kA.y * q4.y + kA.z * q4.z + kA.w * q4.w;
    sA += __shfl_xor(sA, 1); sA += __shfl_xor(sA, 2);
    sA += __shfl_xor(sA, 4); sA += __shfl_xor(sA, 8);
    float mn = fmaxf(m, sA);
    float sc = __expf(m - mn);
    float p  = __expf(sA - mn);
    m = mn;
    l = l * sc + p;
    pv.x = pv.x * sc + p * vA.x; pv.y = pv.y * sc + p * vA.y;
    pv.z = pv.z * sc + p * vA.z; pv.w = pv.w * sc + p * vA.w;
  }

  float* pp = part + ((size_t)(b * NH + h) * NCH + c) * PSTR;
  *(float4*)(pp + j * 4) = pv;
  if (j == 0) { pp[64] = m; pp[65] = l; }
}

// ---------------- o-projection with fused 16-way chunk-combine (R10-proven) ----------------
__global__ __launch_bounds__(256) void oproj_comb(const float* __restrict__ part,
                                                  const float* __restrict__ Wo,
                                                  const float* __restrict__ bo,
                                                  float* __restrict__ out) {
  const int b = blockIdx.x >> 3, ch = blockIdx.x & 7;
  const int tid = threadIdx.x;
  __shared__ float xs[D_MODEL];

  {
    const int h = tid >> 4;
    const int d = (tid & 15) * 4;
    const float* pp = part + (size_t)(b * NH + h) * NCH * PSTR;
    float M = -1e30f;
    #pragma unroll
    for (int cc = 0; cc < NCH; ++cc) M = fmaxf(M, pp[cc * PSTR + 64]);
    float Lsum = 0.f;
    float4 o = make_float4(0.f, 0.f, 0.f, 0.f);
    #pragma unroll
    for (int cc = 0; cc < NCH; ++cc) {
      const float wgt = __expf(pp[cc * PSTR + 64] - M);
      Lsum += pp[cc * PSTR + 65] * wgt;
      float4 pv = *(const float4*)(pp + cc * PSTR + d);
      o.x += pv.x * wgt; o.y += pv.y * wgt; o.z += pv.z * wgt; o.w += pv.w * wgt;
    }
    const float inv = 1.0f / Lsum;
    xs[h * HD + d]     = o.x * inv;
    xs[h * HD + d + 1] = o.y * inv;
    xs[h * HD + d + 2] = o.z * inv;
    xs[h * HD + d + 3] = o.w * inv;
  }
  __syncthreads();

  const int n = ch * 128 + (tid >> 1);
  const int half = tid & 1;
  const float4* wp = (const float4*)(Wo + (size_t)n * D_MODEL + half * 512);
  const float4* xp = (const float4*)xs + half * 128;
  float a = 0.f;
  #pragma unroll 8
  for (int i = 0; i < 128; ++i) {
    float4 w = wp[i], xv = xp[i];
    a += w.x * xv.x + w.y * xv.y + w.z * xv.z + w.w * xv.w;
  }
  a += __shfl_xor(a, 1);
  if (!half) out[(size_t)b * D_MODEL + n] = a + bo[n];
}

// ---------------- launch ----------------
extern "C" void kernel_launch(void* const* d_in, const int* in_sizes, int n_in,
                              void* d_out, int out_size, void* d_ws, size_t ws_size,
                              hipStream_t stream) {
  const float* hs  = (const float*)d_in[0];
  const float* enc = (const float*)d_in[1];
  const float* Wq  = (const float*)d_in[2];
  const float* bq  = (const float*)d_in[3];
  const float* Wk  = (const float*)d_in[4];
  const float* Wv  = (const float*)d_in[5];
  const float* bv  = (const float*)d_in[6];
  const float* Wo  = (const float*)d_in[7];
  const float* bo  = (const float*)d_in[8];

  float* out   = (float*)d_out;
  float* attnO = out;
  float* Kout  = out + 32768;
  float* Vout  = Kout + (size_t)MROWS * D_MODEL;

  char* ws = (char*)d_ws;
  const size_t off_wkvb = (size_t)MROWS * D_MODEL * 2;        // 98,304,000
  const size_t off_qs   = off_wkvb + 4194304;
  const size_t off_part = off_qs + 131072;                    // 512*16*68*4 = 2,228,224 B

  u16*   encb = (u16*)ws;
  u16*   wkvb = (u16*)(ws + off_wkvb);
  float* qs   = (float*)(ws + off_qs);
  float* part = (float*)(ws + off_part);

  cast_all_q<<<ENC_BLOCKS + W_BLOCKS + QPROJ_BLOCKS, 256, 0, stream>>>(enc, Wk, Wv, hs, Wq, bq,
                                                                       encb, wkvb, qs);

  gemm_kv<<<(MROWS / GBM) * (2048 / GBN), 256, 0, stream>>>(encb, wkvb, bv, Kout, Vout);

  attn_part<<<B_SZ * NCH, 256, 0, stream>>>(qs, Kout, Vout, part);
  oproj_comb<<<B_SZ * 8, 256, 0, stream>>>(part, Wo, bo, attnO);
}